// Round 14
// baseline (343.188 us; speedup 1.0000x reference)
//
#include <hip/hip_runtime.h>
#include <hip/hip_bf16.h>
#include <math.h>

#define NND 50000
#define NE  1200000
#define TOT (NE + NND)
#define INCH 128
#define HID 64
#define H2  32
#define NL  3
#define BSZ 10000
#define NB  196          // ceil(NND/256) dst-buckets of 256 nodes
#define NHB 128          // bhist partial blocks
#define NSTAT 128        // bn_stats blocks
#define NAGG 2048        // persistent aggregate blocks (8 per CU)
#define CHUNK 4096       // edges per passA block
#define GROWS 4          // gemm_in rows per block (r12:16 -> r13:8 -> 4; chain length is the lever)
#define EPS_RES 0.1f
#define BN_EPS 1e-5f

typedef unsigned short ushort8v __attribute__((ext_vector_type(8)));
typedef unsigned short ushort4v __attribute__((ext_vector_type(4)));

__device__ __forceinline__ float b2f(unsigned short u) {
    return __uint_as_float((unsigned)u << 16);
}

// fast tanh: 1 - 2/(exp(2x)+1); clamp keeps exp finite. err ~1e-6, << bf16 noise (validated r1-r13)
__device__ __forceinline__ float fast_tanh(float x) {
    float cx = fminf(fmaxf(x, -8.f), 8.f);
    float e = __expf(2.f * cx);
    return 1.f - __fdividef(2.f, e + 1.f);
}

// ---------------- binned CSR build ----------------
// ebuf entry: (src << 8) | (dst & 255)   [src < 2^16, 8-bit local dst -> 24 bits]

__global__ __launch_bounds__(256) void bhist_kernel(const int* __restrict__ dst, int* __restrict__ bh_part, int ne) {
    __shared__ int arr[256];
    arr[threadIdx.x] = 0;
    __syncthreads();
    int i = blockIdx.x * 256 + threadIdx.x;
    int stride = gridDim.x * 256;
    for (int e = i; e < ne; e += stride) atomicAdd(&arr[dst[e] >> 8], 1);
    __syncthreads();
    bh_part[blockIdx.x * 256 + threadIdx.x] = arr[threadIdx.x];
}

__global__ __launch_bounds__(256) void bscan_kernel(const int* __restrict__ bh_part,
                                                    int* __restrict__ bstart, int* __restrict__ bcur,
                                                    int* __restrict__ offsets) {
    __shared__ int ls[256];
    int t = threadIdx.x;
    int v = 0;
    for (int k = 0; k < NHB; k++) v += bh_part[k * 256 + t];
    ls[t] = v;
    __syncthreads();
    for (int off = 1; off < 256; off <<= 1) {
        int tv = (t >= off) ? ls[t - off] : 0;
        __syncthreads();
        ls[t] += tv;
        __syncthreads();
    }
    int excl = ls[t] - v;
    if (t < NB) { bstart[t] = excl; bcur[t] = excl; }
    if (t == NB) bstart[NB] = ls[NB - 1];   // = NE
    if (t == 0) offsets[NND] = TOT;
}

// binned scatter with packed 4B entries
__global__ __launch_bounds__(256) void passA_kernel(const int* __restrict__ src, const int* __restrict__ dst,
                                                    int* __restrict__ bcur, unsigned* __restrict__ ebuf, int ne) {
    __shared__ int arr[256];
    int t = threadIdx.x;
    int base = blockIdx.x * CHUNK;
    int lim = min(base + CHUNK, ne);
    arr[t] = 0;
    __syncthreads();
    for (int e = base + t; e < lim; e += 256) atomicAdd(&arr[dst[e] >> 8], 1);
    __syncthreads();
    int cnt_t = arr[t];
    int claimed = 0;
    if (cnt_t > 0) claimed = atomicAdd(&bcur[t], cnt_t);
    __syncthreads();
    arr[t] = claimed;
    __syncthreads();
    for (int e = base + t; e < lim; e += 256) {
        int d = dst[e];
        int pos = atomicAdd(&arr[d >> 8], 1);
        ebuf[pos] = ((unsigned)src[e] << 8) | (unsigned)(d & 255);
    }
}

// fused: per-bucket degree + local offset scan + dinv(->aldi.y) + self-loop + edge placement
__global__ __launch_bounds__(256) void bucket_build_kernel(const unsigned* __restrict__ ebuf, const int* __restrict__ bstart,
                                                           int* __restrict__ offsets, int* __restrict__ csr,
                                                           float* __restrict__ aldi_f) {
    __shared__ int dcnt[256];
    __shared__ int ls[256];
    __shared__ int cur[256];
    int b = blockIdx.x, t = threadIdx.x;
    dcnt[t] = 0;
    __syncthreads();
    int beg = bstart[b], end = bstart[b + 1];
    for (int p = beg + t; p < end; p += 256) atomicAdd(&dcnt[ebuf[p] & 255u], 1);
    __syncthreads();
    int node = b * 256 + t;
    bool valid = node < NND;
    int d = valid ? (dcnt[t] + 1) : 0;       // +1 self-loop
    ls[t] = d;
    __syncthreads();
    for (int off = 1; off < 256; off <<= 1) {
        int tv = (t >= off) ? ls[t - off] : 0;
        __syncthreads();
        ls[t] += tv;
        __syncthreads();
    }
    int off = bstart[b] + b * 256 + ls[t] - d;   // exclusive
    if (valid) {
        offsets[node] = off;
        aldi_f[2 * node + 1] = rsqrtf((float)d);   // dinv
        csr[off] = node;        // self-loop first
        cur[t] = off + 1;
    }
    __syncthreads();
    for (int p = beg + t; p < end; p += 256) {
        unsigned ed = ebuf[p];
        int pos = atomicAdd(&cur[ed & 255u], 1);
        csr[pos] = (int)(ed >> 8);
    }
}

// ---------------- input projection: x0 = relu(x @ W_in + b_in) -> bf16, fused attn layer 0.
// REGISTER-W design, 4 ROWS/BLOCK: wave owns a k-quarter, lane holds W[k0..k0+31][lane] in 32 VGPRs
// (W = 32KB -> fully L1-resident per CU, so reload across blocks is cheap);
// x rows read via wave-uniform (scalar) loads — 4-row chain fits the SGPR file (r12's 16-row chain stalled);
// LDS only for the 4-way cross-wave partial reduce (4 KB).
__global__ __launch_bounds__(256) void gemm_in_kernel(const float* __restrict__ x, const float* __restrict__ W,
                                                      const float* __restrict__ b,
                                                      const float* __restrict__ attl, const float* __restrict__ attr,
                                                      __hip_bfloat16* __restrict__ x0bf,
                                                      float* __restrict__ aldi_f, float* __restrict__ ar) {
    __shared__ float part[4][GROWS][64];   // 4 KB: [k-quarter][row][col]
    int t = threadIdx.x;
    int lane = t & 63;
    int wq = __builtin_amdgcn_readfirstlane(t >> 6);   // wave's k-quarter (SGPR-uniform)
    size_t rowbase = (size_t)blockIdx.x * GROWS;
    float wreg[32];
#pragma unroll
    for (int kk = 0; kk < 32; kk++)
        wreg[kk] = W[(size_t)(wq * 32 + kk) * HID + lane];   // coalesced; W L1/L2-resident
    const float* xbase = x + rowbase * INCH + wq * 32;
#pragma unroll
    for (int r = 0; r < GROWS; r++) {
        const float4* xr = (const float4*)(xbase + (size_t)r * INCH);
        float4 v0 = xr[0], v1 = xr[1], v2 = xr[2], v3 = xr[3];
        float4 v4 = xr[4], v5 = xr[5], v6 = xr[6], v7 = xr[7];
        float s = 0.f;
        s = fmaf(v0.x, wreg[ 0], s); s = fmaf(v0.y, wreg[ 1], s); s = fmaf(v0.z, wreg[ 2], s); s = fmaf(v0.w, wreg[ 3], s);
        s = fmaf(v1.x, wreg[ 4], s); s = fmaf(v1.y, wreg[ 5], s); s = fmaf(v1.z, wreg[ 6], s); s = fmaf(v1.w, wreg[ 7], s);
        s = fmaf(v2.x, wreg[ 8], s); s = fmaf(v2.y, wreg[ 9], s); s = fmaf(v2.z, wreg[10], s); s = fmaf(v2.w, wreg[11], s);
        s = fmaf(v3.x, wreg[12], s); s = fmaf(v3.y, wreg[13], s); s = fmaf(v3.z, wreg[14], s); s = fmaf(v3.w, wreg[15], s);
        s = fmaf(v4.x, wreg[16], s); s = fmaf(v4.y, wreg[17], s); s = fmaf(v4.z, wreg[18], s); s = fmaf(v4.w, wreg[19], s);
        s = fmaf(v5.x, wreg[20], s); s = fmaf(v5.y, wreg[21], s); s = fmaf(v5.z, wreg[22], s); s = fmaf(v5.w, wreg[23], s);
        s = fmaf(v6.x, wreg[24], s); s = fmaf(v6.y, wreg[25], s); s = fmaf(v6.z, wreg[26], s); s = fmaf(v6.w, wreg[27], s);
        s = fmaf(v7.x, wreg[28], s); s = fmaf(v7.y, wreg[29], s); s = fmaf(v7.z, wreg[30], s); s = fmaf(v7.w, wreg[31], s);
        part[wq][r][lane] = s;
    }
    __syncthreads();
    int col = lane, rg = t >> 6;
    int r0 = rg;                           // 1 row per wave in epilogue (GROWS=4)
    float a0 = part[0][r0][col] + part[1][r0][col] + part[2][r0][col] + part[3][r0][col];
    float bb = b[col];
    a0 = fmaxf(a0 + bb, 0.f);
    size_t r = rowbase + r0;
    x0bf[r * HID + col] = __float2bfloat16(a0);
    float wl = attl[col], wr = attr[col];
    float p0 = a0 * wl, q0 = a0 * wr;
    for (int off = 32; off > 0; off >>= 1) {
        p0 += __shfl_xor(p0, off); q0 += __shfl_xor(q0, off);
    }
    if (col == 0) {
        aldi_f[2 * r] = p0; ar[r] = q0;
    }
}

// ---------------- aggregate: TWO NODES PER WAVE (r8 champion — byte-identical). DO NOT TOUCH. ----------------
__global__ __launch_bounds__(256) void aggregate_kernel(const __hip_bfloat16* __restrict__ hbf,
                                                        const __hip_bfloat16* __restrict__ x0bf,
                                                        const float2* __restrict__ aldi,
                                                        const float* __restrict__ ar,
                                                        const int* __restrict__ offsets, const int* __restrict__ csr,
                                                        float* __restrict__ y, int n) {
    int wave = threadIdx.x >> 6;
    int lane = threadIdx.x & 63;
    int half = lane >> 5;          // node slot within wave (0/1)
    int ll   = lane & 31;          // lane within half
    int sg   = ll >> 3;            // edge subgroup 0..3
    int cl   = (ll & 7) << 3;      // channel base (8 channels per lane)
    int hbase = half << 5;         // shfl base of this half
    const unsigned short* hb = (const unsigned short*)hbf;
    for (int vb = blockIdx.x; (vb << 3) < n; vb += gridDim.x) {
        int v = (vb << 3) + (wave << 1) + half;
        bool vvalid = v < n;
        int beg = 0, end = 0;
        float arv = 0.f;
        if (vvalid) { beg = offsets[v]; end = offsets[v + 1]; arv = ar[v]; }
        int nstr = (end - beg + 31) >> 5;
        int mstr = max(nstr, __shfl_xor(nstr, 32));   // wave-uniform strip count
        float a0 = 0.f, a1 = 0.f, a2 = 0.f, a3 = 0.f, a4 = 0.f, a5 = 0.f, a6 = 0.f, a7 = 0.f;
        for (int s = 0; s < mstr; ++s) {
            int sb = beg + (s << 5);
            int p = sb + ll;
            int u = 0; float c = 0.f;
            if (p < end) {
                u = csr[p];                         // coalesced 32-edge strip per half
                float2 ad = aldi[u];                // (al[u], dinv[u]) one 8B gather
                c = fast_tanh(ad.x + arv) * ad.y;   // one tanh per edge
            }
            int cnt = end - sb;                     // valid edges in this strip (may be <=0 or >32)
            // 2 chunks of 16 edges (4 iters x 4 subgroups), 4 loads in flight per lane
            for (int ch = 0; ch < 2; ++ch) {
                int j0 = (ch << 4) + sg;
                int j1 = j0 + 4, j2 = j0 + 8, j3 = j0 + 12;
                int js0 = (j0 < cnt) ? j0 : 0;
                int js1 = (j1 < cnt) ? j1 : 0;
                int js2 = (j2 < cnt) ? j2 : 0;
                int js3 = (j3 < cnt) ? j3 : 0;
                int u0 = __shfl(u, hbase + js0); float c0 = __shfl(c, hbase + js0); if (j0 >= cnt) c0 = 0.f;
                int u1 = __shfl(u, hbase + js1); float c1 = __shfl(c, hbase + js1); if (j1 >= cnt) c1 = 0.f;
                int u2 = __shfl(u, hbase + js2); float c2 = __shfl(c, hbase + js2); if (j2 >= cnt) c2 = 0.f;
                int u3 = __shfl(u, hbase + js3); float c3 = __shfl(c, hbase + js3); if (j3 >= cnt) c3 = 0.f;
                ushort8v h0 = *(const ushort8v*)(hb + (size_t)u0 * HID + cl);   // 4 independent 16B loads,
                ushort8v h1 = *(const ushort8v*)(hb + (size_t)u1 * HID + cl);   // all in flight together
                ushort8v h2 = *(const ushort8v*)(hb + (size_t)u2 * HID + cl);
                ushort8v h3 = *(const ushort8v*)(hb + (size_t)u3 * HID + cl);
                a0 = fmaf(b2f(h0[0]), c0, a0); a1 = fmaf(b2f(h0[1]), c0, a1);
                a2 = fmaf(b2f(h0[2]), c0, a2); a3 = fmaf(b2f(h0[3]), c0, a3);
                a4 = fmaf(b2f(h0[4]), c0, a4); a5 = fmaf(b2f(h0[5]), c0, a5);
                a6 = fmaf(b2f(h0[6]), c0, a6); a7 = fmaf(b2f(h0[7]), c0, a7);
                a0 = fmaf(b2f(h1[0]), c1, a0); a1 = fmaf(b2f(h1[1]), c1, a1);
                a2 = fmaf(b2f(h1[2]), c1, a2); a3 = fmaf(b2f(h1[3]), c1, a3);
                a4 = fmaf(b2f(h1[4]), c1, a4); a5 = fmaf(b2f(h1[5]), c1, a5);
                a6 = fmaf(b2f(h1[6]), c1, a6); a7 = fmaf(b2f(h1[7]), c1, a7);
                a0 = fmaf(b2f(h2[0]), c2, a0); a1 = fmaf(b2f(h2[1]), c2, a1);
                a2 = fmaf(b2f(h2[2]), c2, a2); a3 = fmaf(b2f(h2[3]), c2, a3);
                a4 = fmaf(b2f(h2[4]), c2, a4); a5 = fmaf(b2f(h2[5]), c2, a5);
                a6 = fmaf(b2f(h2[6]), c2, a6); a7 = fmaf(b2f(h2[7]), c2, a7);
                a0 = fmaf(b2f(h3[0]), c3, a0); a1 = fmaf(b2f(h3[1]), c3, a1);
                a2 = fmaf(b2f(h3[2]), c3, a2); a3 = fmaf(b2f(h3[3]), c3, a3);
                a4 = fmaf(b2f(h3[4]), c3, a4); a5 = fmaf(b2f(h3[5]), c3, a5);
                a6 = fmaf(b2f(h3[6]), c3, a6); a7 = fmaf(b2f(h3[7]), c3, a7);
            }
        }
        // reduce across 4 subgroups (xor 8,16 stays within the half)
        for (int off = 8; off < 32; off <<= 1) {
            a0 += __shfl_xor(a0, off); a1 += __shfl_xor(a1, off);
            a2 += __shfl_xor(a2, off); a3 += __shfl_xor(a3, off);
            a4 += __shfl_xor(a4, off); a5 += __shfl_xor(a5, off);
            a6 += __shfl_xor(a6, off); a7 += __shfl_xor(a7, off);
        }
        if (sg == 0 && vvalid) {
            float dv = aldi[v].y;
            ushort8v xb = *(const ushort8v*)((const unsigned short*)x0bf + (size_t)v * HID + cl);
            float4 o0, o1;
            o0.x = fmaxf(fmaf(EPS_RES, b2f(xb[0]), a0 * dv), 0.f);
            o0.y = fmaxf(fmaf(EPS_RES, b2f(xb[1]), a1 * dv), 0.f);
            o0.z = fmaxf(fmaf(EPS_RES, b2f(xb[2]), a2 * dv), 0.f);
            o0.w = fmaxf(fmaf(EPS_RES, b2f(xb[3]), a3 * dv), 0.f);
            o1.x = fmaxf(fmaf(EPS_RES, b2f(xb[4]), a4 * dv), 0.f);
            o1.y = fmaxf(fmaf(EPS_RES, b2f(xb[5]), a5 * dv), 0.f);
            o1.z = fmaxf(fmaf(EPS_RES, b2f(xb[6]), a6 * dv), 0.f);
            o1.w = fmaxf(fmaf(EPS_RES, b2f(xb[7]), a7 * dv), 0.f);
            *(float4*)(y + (size_t)v * HID + cl) = o0;
            *(float4*)(y + (size_t)v * HID + cl + 4) = o1;
        }
    }
}

// ---------------- bn stats (last-block finalize; PRIVATE acc region per use, zeroed once, no reset) ----------------
template <int C>
__global__ __launch_bounds__(256) void bn_stats_fused_kernel(const float* __restrict__ y, int rows,
                                                             const float* __restrict__ g, const float* __restrict__ b,
                                                             float rows_inv,
                                                             float* __restrict__ acc, int* __restrict__ counter,
                                                             float* __restrict__ scale, float* __restrict__ shift) {
    const int TPR = C / 4;           // lanes per row
    const int RPW = 64 / TPR;        // rows per wave per iter
    int lane = threadIdx.x & 63;
    int wave = threadIdx.x >> 6;
    int cl = (lane % TPR) * 4;
    int rsub = lane / TPR;
    int rpb = 4 * RPW;
    int r = blockIdx.x * rpb + wave * RPW + rsub;
    int stride = gridDim.x * rpb;
    float s0 = 0.f, s1 = 0.f, s2 = 0.f, s3 = 0.f, q0 = 0.f, q1 = 0.f, q2 = 0.f, q3 = 0.f;
    for (; r < rows; r += stride) {
        float4 v = *(const float4*)(y + (size_t)r * C + cl);
        s0 += v.x; q0 = fmaf(v.x, v.x, q0);
        s1 += v.y; q1 = fmaf(v.y, v.y, q1);
        s2 += v.z; q2 = fmaf(v.z, v.z, q2);
        s3 += v.w; q3 = fmaf(v.w, v.w, q3);
    }
    for (int off = TPR; off < 64; off <<= 1) {
        s0 += __shfl_xor(s0, off); q0 += __shfl_xor(q0, off);
        s1 += __shfl_xor(s1, off); q1 += __shfl_xor(q1, off);
        s2 += __shfl_xor(s2, off); q2 += __shfl_xor(q2, off);
        s3 += __shfl_xor(s3, off); q3 += __shfl_xor(q3, off);
    }
    __shared__ float lsum[4][64], lsq[4][64];
    if (lane < TPR) {
        lsum[wave][cl + 0] = s0; lsq[wave][cl + 0] = q0;
        lsum[wave][cl + 1] = s1; lsq[wave][cl + 1] = q1;
        lsum[wave][cl + 2] = s2; lsq[wave][cl + 2] = q2;
        lsum[wave][cl + 3] = s3; lsq[wave][cl + 3] = q3;
    }
    __syncthreads();
    int t = threadIdx.x;
    if (t < C) {
        float ts = lsum[0][t] + lsum[1][t] + lsum[2][t] + lsum[3][t];
        float tq = lsq[0][t] + lsq[1][t] + lsq[2][t] + lsq[3][t];
        atomicAdd(&acc[t], ts);
        atomicAdd(&acc[64 + t], tq);
    }
    __shared__ int islast;
    __syncthreads();
    if (t == 0) {
        __threadfence();
        int old = atomicAdd(counter, 1);
        islast = (old == (int)gridDim.x - 1) ? 1 : 0;
    }
    __syncthreads();
    if (islast && t < C) {
        float ts = atomicAdd(&acc[t], 0.f);        // atomic read (coherent)
        float tq = atomicAdd(&acc[64 + t], 0.f);
        float mean = ts * rows_inv;
        float var = tq * rows_inv - mean * mean;
        float sc = g[t] * rsqrtf(var + BN_EPS);
        scale[t] = sc;
        shift[t] = b[t] - mean * sc;
    }
}

// BN apply + attention dots: 4 rows/wave, 4ch/lane float4, 16-lane reductions, packed 8B bf16 stores
__global__ __launch_bounds__(256) void bnapply_attn_kernel(const float* __restrict__ y, const float* __restrict__ scale,
                                                           const float* __restrict__ shift,
                                                           const float* __restrict__ attl, const float* __restrict__ attr,
                                                           __hip_bfloat16* __restrict__ hbf,
                                                           float* __restrict__ aldi_f, float* __restrict__ arr_out, int n) {
    int lane = threadIdx.x & 63;
    int wave = threadIdx.x >> 6;
    int rsub = lane >> 4;           // row 0..3 within wave
    int cl = (lane & 15) << 2;      // 4 channels per lane
    int r = blockIdx.x * 16 + wave * 4 + rsub;
    if (r >= n) return;
    float4 v = *(const float4*)(y + (size_t)r * HID + cl);
    float4 sc = *(const float4*)(scale + cl);
    float4 sh = *(const float4*)(shift + cl);
    float v0 = fmaf(v.x, sc.x, sh.x);
    float v1 = fmaf(v.y, sc.y, sh.y);
    float v2 = fmaf(v.z, sc.z, sh.z);
    float v3 = fmaf(v.w, sc.w, sh.w);
    __hip_bfloat16 b0 = __float2bfloat16(v0), b1 = __float2bfloat16(v1);
    __hip_bfloat16 b2 = __float2bfloat16(v2), b3 = __float2bfloat16(v3);
    ushort4v hv;
    hv[0] = *(unsigned short*)&b0; hv[1] = *(unsigned short*)&b1;
    hv[2] = *(unsigned short*)&b2; hv[3] = *(unsigned short*)&b3;
    *(ushort4v*)((unsigned short*)hbf + (size_t)r * HID + cl) = hv;
    float4 wl4 = *(const float4*)(attl + cl);
    float4 wr4 = *(const float4*)(attr + cl);
    float pl = v0 * wl4.x + v1 * wl4.y + v2 * wl4.z + v3 * wl4.w;
    float pr = v0 * wr4.x + v1 * wr4.y + v2 * wr4.z + v3 * wr4.w;
    for (int off = 1; off < 16; off <<= 1) {
        pl += __shfl_xor(pl, off);
        pr += __shfl_xor(pr, off);
    }
    if ((lane & 15) == 0) { aldi_f[2 * r] = pl; arr_out[r] = pr; }
}

// ---------------- MLP head ----------------
__global__ __launch_bounds__(256) void mlp1_kernel(const float* __restrict__ y, const float* __restrict__ scale,
                                                   const float* __restrict__ shift, const float* __restrict__ W,
                                                   const float* __restrict__ b, float* __restrict__ z1) {
    __shared__ float Wl[HID * HID];
    __shared__ float xs[16 * HID];
    int t = threadIdx.x;
    for (int i = t; i < HID * HID; i += 256) Wl[i] = W[i];
    size_t rowbase = (size_t)blockIdx.x * 16;
    for (int i = t; i < 16 * HID; i += 256) {
        int c = i & 63;
        xs[i] = fmaf(y[rowbase * HID + i], scale[c], shift[c]);
    }
    __syncthreads();
    int col = t & 63, rg = t >> 6;
    float a0 = 0.f, a1 = 0.f, a2 = 0.f, a3 = 0.f;
    for (int k = 0; k < HID; k++) {
        float wk = Wl[k * HID + col];
        a0 = fmaf(xs[(rg * 4 + 0) * HID + k], wk, a0);
        a1 = fmaf(xs[(rg * 4 + 1) * HID + k], wk, a1);
        a2 = fmaf(xs[(rg * 4 + 2) * HID + k], wk, a2);
        a3 = fmaf(xs[(rg * 4 + 3) * HID + k], wk, a3);
    }
    float bb = b[col];
    size_t r = rowbase + rg * 4;
    z1[(r + 0) * HID + col] = a0 + bb;
    z1[(r + 1) * HID + col] = a1 + bb;
    z1[(r + 2) * HID + col] = a2 + bb;
    z1[(r + 3) * HID + col] = a3 + bb;
}

__global__ __launch_bounds__(256) void mlp2_kernel(const float* __restrict__ z1, const float* __restrict__ scale,
                                                   const float* __restrict__ shift, const float* __restrict__ W,
                                                   const float* __restrict__ b, float* __restrict__ z2) {
    __shared__ float Wl[HID * H2];
    __shared__ float as[16 * HID];
    int t = threadIdx.x;
    for (int i = t; i < HID * H2; i += 256) Wl[i] = W[i];
    size_t rowbase = (size_t)blockIdx.x * 16;
    for (int i = t; i < 16 * HID; i += 256) {
        int c = i & 63;
        float v = z1[rowbase * HID + i];
        as[i] = fmaxf(fmaf(v, scale[c], shift[c]), 0.f);
    }
    __syncthreads();
    int col = t & 31, rg = t >> 5;
    float a0 = 0.f, a1 = 0.f;
    for (int k = 0; k < HID; k++) {
        float wk = Wl[k * H2 + col];
        a0 = fmaf(as[(rg * 2 + 0) * HID + k], wk, a0);
        a1 = fmaf(as[(rg * 2 + 1) * HID + k], wk, a1);
    }
    float bb = b[col];
    size_t r = rowbase + rg * 2;
    z2[(r + 0) * H2 + col] = a0 + bb;
    z2[(r + 1) * H2 + col] = a1 + bb;
}

__global__ __launch_bounds__(256) void mlp3_kernel(const float* __restrict__ z2, const float* __restrict__ scale,
                                                   const float* __restrict__ shift, const float* __restrict__ W3,
                                                   const float* __restrict__ b3, float* __restrict__ out, int rows) {
    int i = blockIdx.x * 256 + threadIdx.x;
    if (i >= rows) return;
    float acc = 0.f;
#pragma unroll
    for (int k = 0; k < H2; k++) {
        float v = fmaxf(fmaf(z2[(size_t)i * H2 + k], scale[k], shift[k]), 0.f);
        acc = fmaf(v, W3[k], acc);
    }
    out[i] = acc + b3[0];
}

// ---------------- launch ----------------
extern "C" void kernel_launch(void* const* d_in, const int* in_sizes, int n_in,
                              void* d_out, int out_size, void* d_ws, size_t ws_size,
                              hipStream_t stream) {
    const float* x     = (const float*)d_in[0];
    const int*   ei    = (const int*)d_in[1];
    const int*   src   = ei;
    const int*   dst   = ei + NE;
    const float* W_in  = (const float*)d_in[3];
    const float* b_in  = (const float*)d_in[4];
    const float* att_l = (const float*)d_in[5];
    const float* att_r = (const float*)d_in[6];
    const float* bn_g  = (const float*)d_in[7];
    const float* bn_b  = (const float*)d_in[8];
    const float* W1    = (const float*)d_in[9];
    const float* b1    = (const float*)d_in[10];
    const float* g1    = (const float*)d_in[11];
    const float* be1   = (const float*)d_in[12];
    const float* W2    = (const float*)d_in[13];
    const float* b2    = (const float*)d_in[14];
    const float* g2    = (const float*)d_in[15];
    const float* be2   = (const float*)d_in[16];
    const float* W3    = (const float*)d_in[17];
    const float* b3    = (const float*)d_in[18];
    float* out = (float*)d_out;

    char* p = (char*)d_ws;
    auto carve = [&](size_t bytes) -> void* {
        void* r = (void*)p;
        p += (bytes + 255) & ~(size_t)255;
        return r;
    };
    int*   bh_part = (int*)carve((size_t)NHB * 256 * 4);
    int*   bstart  = (int*)carve(256 * 4);
    int*   bcur    = (int*)carve(256 * 4);
    int*   offsets = (int*)carve((size_t)(NND + 1) * 4);
    int*   csr     = (int*)carve((size_t)TOT * 4);
    float2* aldi   = (float2*)carve((size_t)NND * 8);   // (al, dinv) packed
    float* ar      = (float*)carve((size_t)NND * 4);
    __hip_bfloat16* x0bf = (__hip_bfloat16*)carve((size_t)NND * HID * 2);
    __hip_bfloat16* hbfA = (__hip_bfloat16*)carve((size_t)NND * HID * 2);
    __hip_bfloat16* hbfB = (__hip_bfloat16*)carve((size_t)NND * HID * 2);
    float* ybuf    = (float*)carve((size_t)NND * HID * 4);
    unsigned* ebuf = (unsigned*)ybuf;   // alias: ebuf (4.8 MB) lifetime ends before ybuf first write
    // 5 PRIVATE bn accumulator regions (128 sums + counter each), zeroed once per launch -> no reset races
    float* accall  = (float*)carve(5 * 256 * 4);
    float* scale   = (float*)carve(64 * 4);
    float* shift   = (float*)carve(64 * 4);
    float* z1      = (float*)carve((size_t)BSZ * HID * 4);
    float* z2      = (float*)carve((size_t)BSZ * H2 * 4);

    auto accr = [&](int i) -> float* { return accall + i * 256; };
    auto ctr  = [&](int i) -> int*   { return (int*)(accall + i * 256 + 128); };

    const int nblkA = (NE + CHUNK - 1) / CHUNK; // 293

    // zero all BN accumulator regions once
    hipMemsetAsync(accall, 0, 5 * 256 * 4, stream);

    // --- binned CSR build; gemm_in launched early to overlap the 1-block bscan ---
    bhist_kernel<<<NHB, 256, 0, stream>>>(dst, bh_part, NE);
    gemm_in_kernel<<<NND / GROWS, 256, 0, stream>>>(x, W_in, b_in, att_l, att_r, x0bf, (float*)aldi, ar);
    bscan_kernel<<<1, 256, 0, stream>>>(bh_part, bstart, bcur, offsets);
    passA_kernel<<<nblkA, 256, 0, stream>>>(src, dst, bcur, ebuf, NE);
    bucket_build_kernel<<<NB, 256, 0, stream>>>(ebuf, bstart, offsets, csr, (float*)aldi);

    // --- 3 layers ---
    const __hip_bfloat16* h_in = x0bf;
    __hip_bfloat16* hbufs[2] = {hbfA, hbfB};
    for (int l = 0; l < NL; l++) {
        aggregate_kernel<<<NAGG, 256, 0, stream>>>(h_in, x0bf, aldi, ar, offsets, csr, ybuf, NND);
        bn_stats_fused_kernel<64><<<NSTAT, 256, 0, stream>>>(ybuf, NND, bn_g + l * HID, bn_b + l * HID,
                                                             1.0f / NND, accr(l), ctr(l), scale, shift);
        if (l < NL - 1) {
            bnapply_attn_kernel<<<(NND + 15) / 16, 256, 0, stream>>>(ybuf, scale, shift,
                                                                     att_l + (l + 1) * HID, att_r + (l + 1) * HID,
                                                                     hbufs[l], (float*)aldi, ar, NND);
            h_in = hbufs[l];
        }
        // last layer: BN fused into mlp1 staging
    }

    // --- MLP head ---
    mlp1_kernel<<<BSZ / 16, 256, 0, stream>>>(ybuf, scale, shift, W1, b1, z1);
    bn_stats_fused_kernel<64><<<NSTAT, 256, 0, stream>>>(z1, BSZ, g1, be1, 1.0f / BSZ, accr(3), ctr(3), scale, shift);

    mlp2_kernel<<<BSZ / 16, 256, 0, stream>>>(z1, scale, shift, W2, b2, z2);
    bn_stats_fused_kernel<32><<<NSTAT, 256, 0, stream>>>(z2, BSZ, g2, be2, 1.0f / BSZ, accr(4), ctr(4), scale, shift);

    mlp3_kernel<<<(BSZ + 255) / 256, 256, 0, stream>>>(z2, scale, shift, W3, b3, out, BSZ);
}

// Round 15
// 339.658 us; speedup vs baseline: 1.0104x; 1.0104x over previous
//
#include <hip/hip_runtime.h>
#include <hip/hip_bf16.h>
#include <math.h>

#define NND 50000
#define NE  1200000
#define TOT (NE + NND)
#define INCH 128
#define HID 64
#define H2  32
#define NL  3
#define BSZ 10000
#define NB  196          // ceil(NND/256) dst-buckets of 256 nodes
#define NHB 128          // bhist partial blocks
#define NSTAT 128        // bn_stats blocks
#define NAGG 2048        // persistent aggregate blocks (8 per CU)
#define CHUNK 4096       // edges per passA block
#define GROWS 8          // gemm_in rows per block (VALIDATED optimum: 16 chain-bound, 4 reload-bound)
#define EPS_RES 0.1f
#define BN_EPS 1e-5f

typedef unsigned short ushort8v __attribute__((ext_vector_type(8)));
typedef unsigned short ushort4v __attribute__((ext_vector_type(4)));

__device__ __forceinline__ float b2f(unsigned short u) {
    return __uint_as_float((unsigned)u << 16);
}

// fast tanh: 1 - 2/(exp(2x)+1); clamp keeps exp finite. err ~1e-6, << bf16 noise (validated r1-r14)
__device__ __forceinline__ float fast_tanh(float x) {
    float cx = fminf(fmaxf(x, -8.f), 8.f);
    float e = __expf(2.f * cx);
    return 1.f - __fdividef(2.f, e + 1.f);
}

// ---------------- binned CSR build ----------------
// ebuf entry: (src << 8) | (dst & 255)   [src < 2^16, 8-bit local dst -> 24 bits]

__global__ __launch_bounds__(256) void bhist_kernel(const int* __restrict__ dst, int* __restrict__ bh_part, int ne) {
    __shared__ int arr[256];
    arr[threadIdx.x] = 0;
    __syncthreads();
    int i = blockIdx.x * 256 + threadIdx.x;
    int stride = gridDim.x * 256;
    for (int e = i; e < ne; e += stride) atomicAdd(&arr[dst[e] >> 8], 1);
    __syncthreads();
    bh_part[blockIdx.x * 256 + threadIdx.x] = arr[threadIdx.x];
}

__global__ __launch_bounds__(256) void bscan_kernel(const int* __restrict__ bh_part,
                                                    int* __restrict__ bstart, int* __restrict__ bcur,
                                                    int* __restrict__ offsets) {
    __shared__ int ls[256];
    int t = threadIdx.x;
    int v = 0;
    for (int k = 0; k < NHB; k++) v += bh_part[k * 256 + t];
    ls[t] = v;
    __syncthreads();
    for (int off = 1; off < 256; off <<= 1) {
        int tv = (t >= off) ? ls[t - off] : 0;
        __syncthreads();
        ls[t] += tv;
        __syncthreads();
    }
    int excl = ls[t] - v;
    if (t < NB) { bstart[t] = excl; bcur[t] = excl; }
    if (t == NB) bstart[NB] = ls[NB - 1];   // = NE
    if (t == 0) offsets[NND] = TOT;
}

// binned scatter with packed 4B entries
__global__ __launch_bounds__(256) void passA_kernel(const int* __restrict__ src, const int* __restrict__ dst,
                                                    int* __restrict__ bcur, unsigned* __restrict__ ebuf, int ne) {
    __shared__ int arr[256];
    int t = threadIdx.x;
    int base = blockIdx.x * CHUNK;
    int lim = min(base + CHUNK, ne);
    arr[t] = 0;
    __syncthreads();
    for (int e = base + t; e < lim; e += 256) atomicAdd(&arr[dst[e] >> 8], 1);
    __syncthreads();
    int cnt_t = arr[t];
    int claimed = 0;
    if (cnt_t > 0) claimed = atomicAdd(&bcur[t], cnt_t);
    __syncthreads();
    arr[t] = claimed;
    __syncthreads();
    for (int e = base + t; e < lim; e += 256) {
        int d = dst[e];
        int pos = atomicAdd(&arr[d >> 8], 1);
        ebuf[pos] = ((unsigned)src[e] << 8) | (unsigned)(d & 255);
    }
}

// fused: per-bucket degree + local offset scan + dinv(->aldi.y) + self-loop + edge placement
__global__ __launch_bounds__(256) void bucket_build_kernel(const unsigned* __restrict__ ebuf, const int* __restrict__ bstart,
                                                           int* __restrict__ offsets, int* __restrict__ csr,
                                                           float* __restrict__ aldi_f) {
    __shared__ int dcnt[256];
    __shared__ int ls[256];
    __shared__ int cur[256];
    int b = blockIdx.x, t = threadIdx.x;
    dcnt[t] = 0;
    __syncthreads();
    int beg = bstart[b], end = bstart[b + 1];
    for (int p = beg + t; p < end; p += 256) atomicAdd(&dcnt[ebuf[p] & 255u], 1);
    __syncthreads();
    int node = b * 256 + t;
    bool valid = node < NND;
    int d = valid ? (dcnt[t] + 1) : 0;       // +1 self-loop
    ls[t] = d;
    __syncthreads();
    for (int off = 1; off < 256; off <<= 1) {
        int tv = (t >= off) ? ls[t - off] : 0;
        __syncthreads();
        ls[t] += tv;
        __syncthreads();
    }
    int off = bstart[b] + b * 256 + ls[t] - d;   // exclusive
    if (valid) {
        offsets[node] = off;
        aldi_f[2 * node + 1] = rsqrtf((float)d);   // dinv
        csr[off] = node;        // self-loop first
        cur[t] = off + 1;
    }
    __syncthreads();
    for (int p = beg + t; p < end; p += 256) {
        unsigned ed = ebuf[p];
        int pos = atomicAdd(&cur[ed & 255u], 1);
        csr[pos] = (int)(ed >> 8);
    }
}

// ---------------- input projection: x0 = relu(x @ W_in + b_in) -> bf16, fused attn layer 0.
// REGISTER-W design, 8 ROWS/BLOCK (validated optimum): wave owns a k-quarter, lane holds
// W[k0..k0+31][lane] in 32 VGPRs; x rows read via wave-uniform (scalar) loads — 8-row chain
// fits the SGPR file; LDS only for the 4-way cross-wave partial reduce (8 KB).
__global__ __launch_bounds__(256) void gemm_in_kernel(const float* __restrict__ x, const float* __restrict__ W,
                                                      const float* __restrict__ b,
                                                      const float* __restrict__ attl, const float* __restrict__ attr,
                                                      __hip_bfloat16* __restrict__ x0bf,
                                                      float* __restrict__ aldi_f, float* __restrict__ ar) {
    __shared__ float part[4][GROWS][64];   // 8 KB: [k-quarter][row][col]
    int t = threadIdx.x;
    int lane = t & 63;
    int wq = __builtin_amdgcn_readfirstlane(t >> 6);   // wave's k-quarter (SGPR-uniform)
    size_t rowbase = (size_t)blockIdx.x * GROWS;
    float wreg[32];
#pragma unroll
    for (int kk = 0; kk < 32; kk++)
        wreg[kk] = W[(size_t)(wq * 32 + kk) * HID + lane];   // coalesced; W L1/L2-resident
    const float* xbase = x + rowbase * INCH + wq * 32;
#pragma unroll
    for (int r = 0; r < GROWS; r++) {
        const float4* xr = (const float4*)(xbase + (size_t)r * INCH);
        float4 v0 = xr[0], v1 = xr[1], v2 = xr[2], v3 = xr[3];
        float4 v4 = xr[4], v5 = xr[5], v6 = xr[6], v7 = xr[7];
        float s = 0.f;
        s = fmaf(v0.x, wreg[ 0], s); s = fmaf(v0.y, wreg[ 1], s); s = fmaf(v0.z, wreg[ 2], s); s = fmaf(v0.w, wreg[ 3], s);
        s = fmaf(v1.x, wreg[ 4], s); s = fmaf(v1.y, wreg[ 5], s); s = fmaf(v1.z, wreg[ 6], s); s = fmaf(v1.w, wreg[ 7], s);
        s = fmaf(v2.x, wreg[ 8], s); s = fmaf(v2.y, wreg[ 9], s); s = fmaf(v2.z, wreg[10], s); s = fmaf(v2.w, wreg[11], s);
        s = fmaf(v3.x, wreg[12], s); s = fmaf(v3.y, wreg[13], s); s = fmaf(v3.z, wreg[14], s); s = fmaf(v3.w, wreg[15], s);
        s = fmaf(v4.x, wreg[16], s); s = fmaf(v4.y, wreg[17], s); s = fmaf(v4.z, wreg[18], s); s = fmaf(v4.w, wreg[19], s);
        s = fmaf(v5.x, wreg[20], s); s = fmaf(v5.y, wreg[21], s); s = fmaf(v5.z, wreg[22], s); s = fmaf(v5.w, wreg[23], s);
        s = fmaf(v6.x, wreg[24], s); s = fmaf(v6.y, wreg[25], s); s = fmaf(v6.z, wreg[26], s); s = fmaf(v6.w, wreg[27], s);
        s = fmaf(v7.x, wreg[28], s); s = fmaf(v7.y, wreg[29], s); s = fmaf(v7.z, wreg[30], s); s = fmaf(v7.w, wreg[31], s);
        part[wq][r][lane] = s;
    }
    __syncthreads();
    int col = lane, rg = t >> 6;
    int r0 = rg * 2;                       // 2 rows per thread-group
    float a0 = part[0][r0 + 0][col] + part[1][r0 + 0][col] + part[2][r0 + 0][col] + part[3][r0 + 0][col];
    float a1 = part[0][r0 + 1][col] + part[1][r0 + 1][col] + part[2][r0 + 1][col] + part[3][r0 + 1][col];
    float bb = b[col];
    a0 = fmaxf(a0 + bb, 0.f); a1 = fmaxf(a1 + bb, 0.f);
    size_t r = rowbase + r0;
    x0bf[(r + 0) * HID + col] = __float2bfloat16(a0);
    x0bf[(r + 1) * HID + col] = __float2bfloat16(a1);
    float wl = attl[col], wr = attr[col];
    float p0 = a0 * wl, q0 = a0 * wr, p1 = a1 * wl, q1 = a1 * wr;
    for (int off = 32; off > 0; off >>= 1) {
        p0 += __shfl_xor(p0, off); q0 += __shfl_xor(q0, off);
        p1 += __shfl_xor(p1, off); q1 += __shfl_xor(q1, off);
    }
    if (col == 0) {
        aldi_f[2 * (r + 0)] = p0; ar[r + 0] = q0;
        aldi_f[2 * (r + 1)] = p1; ar[r + 1] = q1;
    }
}

// ---------------- aggregate: TWO NODES PER WAVE (r8 champion — byte-identical). DO NOT TOUCH. ----------------
__global__ __launch_bounds__(256) void aggregate_kernel(const __hip_bfloat16* __restrict__ hbf,
                                                        const __hip_bfloat16* __restrict__ x0bf,
                                                        const float2* __restrict__ aldi,
                                                        const float* __restrict__ ar,
                                                        const int* __restrict__ offsets, const int* __restrict__ csr,
                                                        float* __restrict__ y, int n) {
    int wave = threadIdx.x >> 6;
    int lane = threadIdx.x & 63;
    int half = lane >> 5;          // node slot within wave (0/1)
    int ll   = lane & 31;          // lane within half
    int sg   = ll >> 3;            // edge subgroup 0..3
    int cl   = (ll & 7) << 3;      // channel base (8 channels per lane)
    int hbase = half << 5;         // shfl base of this half
    const unsigned short* hb = (const unsigned short*)hbf;
    for (int vb = blockIdx.x; (vb << 3) < n; vb += gridDim.x) {
        int v = (vb << 3) + (wave << 1) + half;
        bool vvalid = v < n;
        int beg = 0, end = 0;
        float arv = 0.f;
        if (vvalid) { beg = offsets[v]; end = offsets[v + 1]; arv = ar[v]; }
        int nstr = (end - beg + 31) >> 5;
        int mstr = max(nstr, __shfl_xor(nstr, 32));   // wave-uniform strip count
        float a0 = 0.f, a1 = 0.f, a2 = 0.f, a3 = 0.f, a4 = 0.f, a5 = 0.f, a6 = 0.f, a7 = 0.f;
        for (int s = 0; s < mstr; ++s) {
            int sb = beg + (s << 5);
            int p = sb + ll;
            int u = 0; float c = 0.f;
            if (p < end) {
                u = csr[p];                         // coalesced 32-edge strip per half
                float2 ad = aldi[u];                // (al[u], dinv[u]) one 8B gather
                c = fast_tanh(ad.x + arv) * ad.y;   // one tanh per edge
            }
            int cnt = end - sb;                     // valid edges in this strip (may be <=0 or >32)
            // 2 chunks of 16 edges (4 iters x 4 subgroups), 4 loads in flight per lane
            for (int ch = 0; ch < 2; ++ch) {
                int j0 = (ch << 4) + sg;
                int j1 = j0 + 4, j2 = j0 + 8, j3 = j0 + 12;
                int js0 = (j0 < cnt) ? j0 : 0;
                int js1 = (j1 < cnt) ? j1 : 0;
                int js2 = (j2 < cnt) ? j2 : 0;
                int js3 = (j3 < cnt) ? j3 : 0;
                int u0 = __shfl(u, hbase + js0); float c0 = __shfl(c, hbase + js0); if (j0 >= cnt) c0 = 0.f;
                int u1 = __shfl(u, hbase + js1); float c1 = __shfl(c, hbase + js1); if (j1 >= cnt) c1 = 0.f;
                int u2 = __shfl(u, hbase + js2); float c2 = __shfl(c, hbase + js2); if (j2 >= cnt) c2 = 0.f;
                int u3 = __shfl(u, hbase + js3); float c3 = __shfl(c, hbase + js3); if (j3 >= cnt) c3 = 0.f;
                ushort8v h0 = *(const ushort8v*)(hb + (size_t)u0 * HID + cl);   // 4 independent 16B loads,
                ushort8v h1 = *(const ushort8v*)(hb + (size_t)u1 * HID + cl);   // all in flight together
                ushort8v h2 = *(const ushort8v*)(hb + (size_t)u2 * HID + cl);
                ushort8v h3 = *(const ushort8v*)(hb + (size_t)u3 * HID + cl);
                a0 = fmaf(b2f(h0[0]), c0, a0); a1 = fmaf(b2f(h0[1]), c0, a1);
                a2 = fmaf(b2f(h0[2]), c0, a2); a3 = fmaf(b2f(h0[3]), c0, a3);
                a4 = fmaf(b2f(h0[4]), c0, a4); a5 = fmaf(b2f(h0[5]), c0, a5);
                a6 = fmaf(b2f(h0[6]), c0, a6); a7 = fmaf(b2f(h0[7]), c0, a7);
                a0 = fmaf(b2f(h1[0]), c1, a0); a1 = fmaf(b2f(h1[1]), c1, a1);
                a2 = fmaf(b2f(h1[2]), c1, a2); a3 = fmaf(b2f(h1[3]), c1, a3);
                a4 = fmaf(b2f(h1[4]), c1, a4); a5 = fmaf(b2f(h1[5]), c1, a5);
                a6 = fmaf(b2f(h1[6]), c1, a6); a7 = fmaf(b2f(h1[7]), c1, a7);
                a0 = fmaf(b2f(h2[0]), c2, a0); a1 = fmaf(b2f(h2[1]), c2, a1);
                a2 = fmaf(b2f(h2[2]), c2, a2); a3 = fmaf(b2f(h2[3]), c2, a3);
                a4 = fmaf(b2f(h2[4]), c2, a4); a5 = fmaf(b2f(h2[5]), c2, a5);
                a6 = fmaf(b2f(h2[6]), c2, a6); a7 = fmaf(b2f(h2[7]), c2, a7);
                a0 = fmaf(b2f(h3[0]), c3, a0); a1 = fmaf(b2f(h3[1]), c3, a1);
                a2 = fmaf(b2f(h3[2]), c3, a2); a3 = fmaf(b2f(h3[3]), c3, a3);
                a4 = fmaf(b2f(h3[4]), c3, a4); a5 = fmaf(b2f(h3[5]), c3, a5);
                a6 = fmaf(b2f(h3[6]), c3, a6); a7 = fmaf(b2f(h3[7]), c3, a7);
            }
        }
        // reduce across 4 subgroups (xor 8,16 stays within the half)
        for (int off = 8; off < 32; off <<= 1) {
            a0 += __shfl_xor(a0, off); a1 += __shfl_xor(a1, off);
            a2 += __shfl_xor(a2, off); a3 += __shfl_xor(a3, off);
            a4 += __shfl_xor(a4, off); a5 += __shfl_xor(a5, off);
            a6 += __shfl_xor(a6, off); a7 += __shfl_xor(a7, off);
        }
        if (sg == 0 && vvalid) {
            float dv = aldi[v].y;
            ushort8v xb = *(const ushort8v*)((const unsigned short*)x0bf + (size_t)v * HID + cl);
            float4 o0, o1;
            o0.x = fmaxf(fmaf(EPS_RES, b2f(xb[0]), a0 * dv), 0.f);
            o0.y = fmaxf(fmaf(EPS_RES, b2f(xb[1]), a1 * dv), 0.f);
            o0.z = fmaxf(fmaf(EPS_RES, b2f(xb[2]), a2 * dv), 0.f);
            o0.w = fmaxf(fmaf(EPS_RES, b2f(xb[3]), a3 * dv), 0.f);
            o1.x = fmaxf(fmaf(EPS_RES, b2f(xb[4]), a4 * dv), 0.f);
            o1.y = fmaxf(fmaf(EPS_RES, b2f(xb[5]), a5 * dv), 0.f);
            o1.z = fmaxf(fmaf(EPS_RES, b2f(xb[6]), a6 * dv), 0.f);
            o1.w = fmaxf(fmaf(EPS_RES, b2f(xb[7]), a7 * dv), 0.f);
            *(float4*)(y + (size_t)v * HID + cl) = o0;
            *(float4*)(y + (size_t)v * HID + cl + 4) = o1;
        }
    }
}

// ---------------- bn stats (last-block finalize; PRIVATE acc region per use, zeroed once, no reset) ----------------
template <int C>
__global__ __launch_bounds__(256) void bn_stats_fused_kernel(const float* __restrict__ y, int rows,
                                                             const float* __restrict__ g, const float* __restrict__ b,
                                                             float rows_inv,
                                                             float* __restrict__ acc, int* __restrict__ counter,
                                                             float* __restrict__ scale, float* __restrict__ shift) {
    const int TPR = C / 4;           // lanes per row
    const int RPW = 64 / TPR;        // rows per wave per iter
    int lane = threadIdx.x & 63;
    int wave = threadIdx.x >> 6;
    int cl = (lane % TPR) * 4;
    int rsub = lane / TPR;
    int rpb = 4 * RPW;
    int r = blockIdx.x * rpb + wave * RPW + rsub;
    int stride = gridDim.x * rpb;
    float s0 = 0.f, s1 = 0.f, s2 = 0.f, s3 = 0.f, q0 = 0.f, q1 = 0.f, q2 = 0.f, q3 = 0.f;
    for (; r < rows; r += stride) {
        float4 v = *(const float4*)(y + (size_t)r * C + cl);
        s0 += v.x; q0 = fmaf(v.x, v.x, q0);
        s1 += v.y; q1 = fmaf(v.y, v.y, q1);
        s2 += v.z; q2 = fmaf(v.z, v.z, q2);
        s3 += v.w; q3 = fmaf(v.w, v.w, q3);
    }
    for (int off = TPR; off < 64; off <<= 1) {
        s0 += __shfl_xor(s0, off); q0 += __shfl_xor(q0, off);
        s1 += __shfl_xor(s1, off); q1 += __shfl_xor(q1, off);
        s2 += __shfl_xor(s2, off); q2 += __shfl_xor(q2, off);
        s3 += __shfl_xor(s3, off); q3 += __shfl_xor(q3, off);
    }
    __shared__ float lsum[4][64], lsq[4][64];
    if (lane < TPR) {
        lsum[wave][cl + 0] = s0; lsq[wave][cl + 0] = q0;
        lsum[wave][cl + 1] = s1; lsq[wave][cl + 1] = q1;
        lsum[wave][cl + 2] = s2; lsq[wave][cl + 2] = q2;
        lsum[wave][cl + 3] = s3; lsq[wave][cl + 3] = q3;
    }
    __syncthreads();
    int t = threadIdx.x;
    if (t < C) {
        float ts = lsum[0][t] + lsum[1][t] + lsum[2][t] + lsum[3][t];
        float tq = lsq[0][t] + lsq[1][t] + lsq[2][t] + lsq[3][t];
        atomicAdd(&acc[t], ts);
        atomicAdd(&acc[64 + t], tq);
    }
    __shared__ int islast;
    __syncthreads();
    if (t == 0) {
        __threadfence();
        int old = atomicAdd(counter, 1);
        islast = (old == (int)gridDim.x - 1) ? 1 : 0;
    }
    __syncthreads();
    if (islast && t < C) {
        float ts = atomicAdd(&acc[t], 0.f);        // atomic read (coherent)
        float tq = atomicAdd(&acc[64 + t], 0.f);
        float mean = ts * rows_inv;
        float var = tq * rows_inv - mean * mean;
        float sc = g[t] * rsqrtf(var + BN_EPS);
        scale[t] = sc;
        shift[t] = b[t] - mean * sc;
    }
}

// BN apply + attention dots: 4 rows/wave, 4ch/lane float4, 16-lane reductions, packed 8B bf16 stores
__global__ __launch_bounds__(256) void bnapply_attn_kernel(const float* __restrict__ y, const float* __restrict__ scale,
                                                           const float* __restrict__ shift,
                                                           const float* __restrict__ attl, const float* __restrict__ attr,
                                                           __hip_bfloat16* __restrict__ hbf,
                                                           float* __restrict__ aldi_f, float* __restrict__ arr_out, int n) {
    int lane = threadIdx.x & 63;
    int wave = threadIdx.x >> 6;
    int rsub = lane >> 4;           // row 0..3 within wave
    int cl = (lane & 15) << 2;      // 4 channels per lane
    int r = blockIdx.x * 16 + wave * 4 + rsub;
    if (r >= n) return;
    float4 v = *(const float4*)(y + (size_t)r * HID + cl);
    float4 sc = *(const float4*)(scale + cl);
    float4 sh = *(const float4*)(shift + cl);
    float v0 = fmaf(v.x, sc.x, sh.x);
    float v1 = fmaf(v.y, sc.y, sh.y);
    float v2 = fmaf(v.z, sc.z, sh.z);
    float v3 = fmaf(v.w, sc.w, sh.w);
    __hip_bfloat16 b0 = __float2bfloat16(v0), b1 = __float2bfloat16(v1);
    __hip_bfloat16 b2 = __float2bfloat16(v2), b3 = __float2bfloat16(v3);
    ushort4v hv;
    hv[0] = *(unsigned short*)&b0; hv[1] = *(unsigned short*)&b1;
    hv[2] = *(unsigned short*)&b2; hv[3] = *(unsigned short*)&b3;
    *(ushort4v*)((unsigned short*)hbf + (size_t)r * HID + cl) = hv;
    float4 wl4 = *(const float4*)(attl + cl);
    float4 wr4 = *(const float4*)(attr + cl);
    float pl = v0 * wl4.x + v1 * wl4.y + v2 * wl4.z + v3 * wl4.w;
    float pr = v0 * wr4.x + v1 * wr4.y + v2 * wr4.z + v3 * wr4.w;
    for (int off = 1; off < 16; off <<= 1) {
        pl += __shfl_xor(pl, off);
        pr += __shfl_xor(pr, off);
    }
    if ((lane & 15) == 0) { aldi_f[2 * r] = pl; arr_out[r] = pr; }
}

// ---------------- MLP head ----------------
__global__ __launch_bounds__(256) void mlp1_kernel(const float* __restrict__ y, const float* __restrict__ scale,
                                                   const float* __restrict__ shift, const float* __restrict__ W,
                                                   const float* __restrict__ b, float* __restrict__ z1) {
    __shared__ float Wl[HID * HID];
    __shared__ float xs[16 * HID];
    int t = threadIdx.x;
    for (int i = t; i < HID * HID; i += 256) Wl[i] = W[i];
    size_t rowbase = (size_t)blockIdx.x * 16;
    for (int i = t; i < 16 * HID; i += 256) {
        int c = i & 63;
        xs[i] = fmaf(y[rowbase * HID + i], scale[c], shift[c]);
    }
    __syncthreads();
    int col = t & 63, rg = t >> 6;
    float a0 = 0.f, a1 = 0.f, a2 = 0.f, a3 = 0.f;
    for (int k = 0; k < HID; k++) {
        float wk = Wl[k * HID + col];
        a0 = fmaf(xs[(rg * 4 + 0) * HID + k], wk, a0);
        a1 = fmaf(xs[(rg * 4 + 1) * HID + k], wk, a1);
        a2 = fmaf(xs[(rg * 4 + 2) * HID + k], wk, a2);
        a3 = fmaf(xs[(rg * 4 + 3) * HID + k], wk, a3);
    }
    float bb = b[col];
    size_t r = rowbase + rg * 4;
    z1[(r + 0) * HID + col] = a0 + bb;
    z1[(r + 1) * HID + col] = a1 + bb;
    z1[(r + 2) * HID + col] = a2 + bb;
    z1[(r + 3) * HID + col] = a3 + bb;
}

__global__ __launch_bounds__(256) void mlp2_kernel(const float* __restrict__ z1, const float* __restrict__ scale,
                                                   const float* __restrict__ shift, const float* __restrict__ W,
                                                   const float* __restrict__ b, float* __restrict__ z2) {
    __shared__ float Wl[HID * H2];
    __shared__ float as[16 * HID];
    int t = threadIdx.x;
    for (int i = t; i < HID * H2; i += 256) Wl[i] = W[i];
    size_t rowbase = (size_t)blockIdx.x * 16;
    for (int i = t; i < 16 * HID; i += 256) {
        int c = i & 63;
        float v = z1[rowbase * HID + i];
        as[i] = fmaxf(fmaf(v, scale[c], shift[c]), 0.f);
    }
    __syncthreads();
    int col = t & 31, rg = t >> 5;
    float a0 = 0.f, a1 = 0.f;
    for (int k = 0; k < HID; k++) {
        float wk = Wl[k * H2 + col];
        a0 = fmaf(as[(rg * 2 + 0) * HID + k], wk, a0);
        a1 = fmaf(as[(rg * 2 + 1) * HID + k], wk, a1);
    }
    float bb = b[col];
    size_t r = rowbase + rg * 2;
    z2[(r + 0) * H2 + col] = a0 + bb;
    z2[(r + 1) * H2 + col] = a1 + bb;
}

__global__ __launch_bounds__(256) void mlp3_kernel(const float* __restrict__ z2, const float* __restrict__ scale,
                                                   const float* __restrict__ shift, const float* __restrict__ W3,
                                                   const float* __restrict__ b3, float* __restrict__ out, int rows) {
    int i = blockIdx.x * 256 + threadIdx.x;
    if (i >= rows) return;
    float acc = 0.f;
#pragma unroll
    for (int k = 0; k < H2; k++) {
        float v = fmaxf(fmaf(z2[(size_t)i * H2 + k], scale[k], shift[k]), 0.f);
        acc = fmaf(v, W3[k], acc);
    }
    out[i] = acc + b3[0];
}

// ---------------- launch ----------------
extern "C" void kernel_launch(void* const* d_in, const int* in_sizes, int n_in,
                              void* d_out, int out_size, void* d_ws, size_t ws_size,
                              hipStream_t stream) {
    const float* x     = (const float*)d_in[0];
    const int*   ei    = (const int*)d_in[1];
    const int*   src   = ei;
    const int*   dst   = ei + NE;
    const float* W_in  = (const float*)d_in[3];
    const float* b_in  = (const float*)d_in[4];
    const float* att_l = (const float*)d_in[5];
    const float* att_r = (const float*)d_in[6];
    const float* bn_g  = (const float*)d_in[7];
    const float* bn_b  = (const float*)d_in[8];
    const float* W1    = (const float*)d_in[9];
    const float* b1    = (const float*)d_in[10];
    const float* g1    = (const float*)d_in[11];
    const float* be1   = (const float*)d_in[12];
    const float* W2    = (const float*)d_in[13];
    const float* b2    = (const float*)d_in[14];
    const float* g2    = (const float*)d_in[15];
    const float* be2   = (const float*)d_in[16];
    const float* W3    = (const float*)d_in[17];
    const float* b3    = (const float*)d_in[18];
    float* out = (float*)d_out;

    char* p = (char*)d_ws;
    auto carve = [&](size_t bytes) -> void* {
        void* r = (void*)p;
        p += (bytes + 255) & ~(size_t)255;
        return r;
    };
    int*   bh_part = (int*)carve((size_t)NHB * 256 * 4);
    int*   bstart  = (int*)carve(256 * 4);
    int*   bcur    = (int*)carve(256 * 4);
    int*   offsets = (int*)carve((size_t)(NND + 1) * 4);
    int*   csr     = (int*)carve((size_t)TOT * 4);
    float2* aldi   = (float2*)carve((size_t)NND * 8);   // (al, dinv) packed
    float* ar      = (float*)carve((size_t)NND * 4);
    __hip_bfloat16* x0bf = (__hip_bfloat16*)carve((size_t)NND * HID * 2);
    __hip_bfloat16* hbfA = (__hip_bfloat16*)carve((size_t)NND * HID * 2);
    __hip_bfloat16* hbfB = (__hip_bfloat16*)carve((size_t)NND * HID * 2);
    float* ybuf    = (float*)carve((size_t)NND * HID * 4);
    unsigned* ebuf = (unsigned*)ybuf;   // alias: ebuf (4.8 MB) lifetime ends before ybuf first write
    // 5 PRIVATE bn accumulator regions (128 sums + counter each), zeroed once per launch -> no reset races
    float* accall  = (float*)carve(5 * 256 * 4);
    float* scale   = (float*)carve(64 * 4);
    float* shift   = (float*)carve(64 * 4);
    float* z1      = (float*)carve((size_t)BSZ * HID * 4);
    float* z2      = (float*)carve((size_t)BSZ * H2 * 4);

    auto accr = [&](int i) -> float* { return accall + i * 256; };
    auto ctr  = [&](int i) -> int*   { return (int*)(accall + i * 256 + 128); };

    const int nblkA = (NE + CHUNK - 1) / CHUNK; // 293

    // zero all BN accumulator regions once
    hipMemsetAsync(accall, 0, 5 * 256 * 4, stream);

    // --- binned CSR build; gemm_in launched early to overlap the 1-block bscan ---
    bhist_kernel<<<NHB, 256, 0, stream>>>(dst, bh_part, NE);
    gemm_in_kernel<<<NND / GROWS, 256, 0, stream>>>(x, W_in, b_in, att_l, att_r, x0bf, (float*)aldi, ar);
    bscan_kernel<<<1, 256, 0, stream>>>(bh_part, bstart, bcur, offsets);
    passA_kernel<<<nblkA, 256, 0, stream>>>(src, dst, bcur, ebuf, NE);
    bucket_build_kernel<<<NB, 256, 0, stream>>>(ebuf, bstart, offsets, csr, (float*)aldi);

    // --- 3 layers ---
    const __hip_bfloat16* h_in = x0bf;
    __hip_bfloat16* hbufs[2] = {hbfA, hbfB};
    for (int l = 0; l < NL; l++) {
        aggregate_kernel<<<NAGG, 256, 0, stream>>>(h_in, x0bf, aldi, ar, offsets, csr, ybuf, NND);
        bn_stats_fused_kernel<64><<<NSTAT, 256, 0, stream>>>(ybuf, NND, bn_g + l * HID, bn_b + l * HID,
                                                             1.0f / NND, accr(l), ctr(l), scale, shift);
        if (l < NL - 1) {
            bnapply_attn_kernel<<<(NND + 15) / 16, 256, 0, stream>>>(ybuf, scale, shift,
                                                                     att_l + (l + 1) * HID, att_r + (l + 1) * HID,
                                                                     hbufs[l], (float*)aldi, ar, NND);
            h_in = hbufs[l];
        }
        // last layer: BN fused into mlp1 staging
    }

    // --- MLP head ---
    mlp1_kernel<<<BSZ / 16, 256, 0, stream>>>(ybuf, scale, shift, W1, b1, z1);
    bn_stats_fused_kernel<64><<<NSTAT, 256, 0, stream>>>(z1, BSZ, g1, be1, 1.0f / BSZ, accr(3), ctr(3), scale, shift);

    mlp2_kernel<<<BSZ / 16, 256, 0, stream>>>(z1, scale, shift, W2, b2, z2);
    bn_stats_fused_kernel<32><<<NSTAT, 256, 0, stream>>>(z2, BSZ, g2, be2, 1.0f / BSZ, accr(4), ctr(4), scale, shift);

    mlp3_kernel<<<(BSZ + 255) / 256, 256, 0, stream>>>(z2, scale, shift, W3, b3, out, BSZ);
}